// Round 1
// baseline (647.974 us; speedup 1.0000x reference)
//
#include <hip/hip_runtime.h>

#define NN 50000
#define NE 800000
#define NF 128
#define NH 64
#define BN_EPS 1e-5f

// ---------------- CSR build ----------------

__global__ void k_zero(int* __restrict__ counts, float* __restrict__ partials) {
  int i = blockIdx.x * 256 + threadIdx.x;
  if (i < NN) counts[i] = 0;
  if (i < 128) partials[i] = 0.f;
}

__global__ void k_count(const int* __restrict__ dst, int* __restrict__ counts) {
  int e = blockIdx.x * 256 + threadIdx.x;
  if (e < NE) atomicAdd(&counts[dst[e]], 1);
}

__global__ __launch_bounds__(1024) void k_scan(const int* __restrict__ counts,
                                               int* __restrict__ rowptr,
                                               int* __restrict__ pos) {
  const int T = 1024;
  __shared__ int ls[T];
  int t = threadIdx.x;
  const int chunk = (NN + T - 1) / T;  // 49
  int start = t * chunk;
  int end = start + chunk;
  if (start > NN) start = NN;
  if (end > NN) end = NN;
  int s = 0;
  for (int i = start; i < end; ++i) s += counts[i];
  ls[t] = s;
  __syncthreads();
  for (int off = 1; off < T; off <<= 1) {
    int v = (t >= off) ? ls[t - off] : 0;
    __syncthreads();
    ls[t] += v;
    __syncthreads();
  }
  int run = (t == 0) ? 0 : ls[t - 1];
  for (int i = start; i < end; ++i) {
    rowptr[i] = run;
    pos[i] = run;
    run += counts[i];
  }
  if (t == T - 1) rowptr[NN] = run;
}

__global__ void k_bucket(const int* __restrict__ src, const int* __restrict__ dst,
                         int* __restrict__ pos, int* __restrict__ ebuf) {
  int e = blockIdx.x * 256 + threadIdx.x;
  if (e < NE) {
    int d = dst[e];
    int idx = atomicAdd(&pos[d], 1);
    ebuf[idx] = src[e];
  }
}

// ---------------- aggregation: m[i] = h[i] + sum_{j->i} h[j] ----------------

__global__ void k_agg(const float* __restrict__ h, const int* __restrict__ rowptr,
                      const int* __restrict__ ebuf, float* __restrict__ m) {
  int node = blockIdx.x * 4 + (threadIdx.x >> 6);
  int lane = threadIdx.x & 63;
  if (node >= NN) return;
  float acc = h[(size_t)node * NH + lane];
  int beg = rowptr[node], end = rowptr[node + 1];
  for (int j = beg; j < end; ++j) {
    int s = ebuf[j];
    acc += h[(size_t)s * NH + lane];
  }
  m[(size_t)node * NH + lane] = acc;
}

// ---------------- input transform: z = x @ Wt + bt, + BN partials ----------------

__global__ __launch_bounds__(256) void k_in(const float* __restrict__ x,
                                            const float* __restrict__ Wt,
                                            const float* __restrict__ bt,
                                            float* __restrict__ z,
                                            float* __restrict__ partials) {
  __shared__ float xs[64 * NF];  // 32 KB
  __shared__ float Ws[NF * NH];  // 32 KB
  int t = threadIdx.x;
  int n0base = blockIdx.x * 64;
  int ocol = t & 63;
  int n0 = (t >> 6) * 16;
  {
    const float4* x4 = (const float4*)(x + (size_t)n0base * NF);
    float4* xs4 = (float4*)xs;
#pragma unroll
    for (int i = 0; i < 8; ++i) {
      int idx = t + i * 256;            // float4 index 0..2047
      int node = n0base + (idx >> 5);   // 32 float4 per node row
      float4 v = make_float4(0.f, 0.f, 0.f, 0.f);
      if (node < NN) v = x4[idx];
      xs4[idx] = v;
    }
    const float4* w4 = (const float4*)Wt;
    float4* Ws4 = (float4*)Ws;
#pragma unroll
    for (int i = 0; i < 8; ++i) Ws4[t + i * 256] = w4[t + i * 256];
  }
  __syncthreads();

  float acc[16];
#pragma unroll
  for (int j = 0; j < 16; ++j) acc[j] = 0.f;
  for (int k4 = 0; k4 < NF / 4; ++k4) {
    float w0 = Ws[(k4 * 4 + 0) * NH + ocol];
    float w1 = Ws[(k4 * 4 + 1) * NH + ocol];
    float w2 = Ws[(k4 * 4 + 2) * NH + ocol];
    float w3 = Ws[(k4 * 4 + 3) * NH + ocol];
#pragma unroll
    for (int j = 0; j < 16; ++j) {
      float4 mv = *(const float4*)&xs[(n0 + j) * NF + k4 * 4];
      acc[j] = fmaf(mv.w, w3, fmaf(mv.z, w2, fmaf(mv.y, w1, fmaf(mv.x, w0, acc[j]))));
    }
  }
  float b = bt[ocol];
  float ls = 0.f, lss = 0.f;
#pragma unroll
  for (int j = 0; j < 16; ++j) {
    float v = acc[j] + b;
    acc[j] = v;
    if (n0base + n0 + j < NN) { ls += v; lss += v * v; }
  }
  __syncthreads();  // everyone done reading Ws
  float* red = Ws;  // reuse as [2][4][64]
  red[(t >> 6) * 64 + ocol] = ls;
  red[256 + (t >> 6) * 64 + ocol] = lss;
  __syncthreads();
  if (t < 64) {
    float s = red[t] + red[64 + t] + red[128 + t] + red[192 + t];
    float ss = red[256 + t] + red[320 + t] + red[384 + t] + red[448 + t];
    atomicAdd(&partials[t], s);
    atomicAdd(&partials[64 + t], ss);
  }
#pragma unroll
  for (int j = 0; j < 16; ++j) {
    int node = n0base + n0 + j;
    if (node < NN) z[(size_t)node * NH + ocol] = acc[j];
  }
}

// ---------------- MLP: r = relu(relu(m@W1)@W2), + BN partials ----------------

__global__ __launch_bounds__(256) void k_mlp(const float* __restrict__ m,
                                             const float* __restrict__ W1,
                                             const float* __restrict__ W2,
                                             float* __restrict__ r,
                                             float* __restrict__ partials) {
  __shared__ float ms[64 * NH];  // 16 KB
  __shared__ float ts[64 * NH];  // 16 KB
  __shared__ float Ws[NH * NH];  // 16 KB
  int t = threadIdx.x;
  int n0base = blockIdx.x * 64;
  int ocol = t & 63;
  int n0 = (t >> 6) * 16;
  {
    const float4* m4 = (const float4*)(m + (size_t)n0base * NH);
    float4* ms4 = (float4*)ms;
#pragma unroll
    for (int i = 0; i < 4; ++i) {
      int idx = t + i * 256;            // float4 index 0..1023
      int node = n0base + (idx >> 4);   // 16 float4 per node row
      float4 v = make_float4(0.f, 0.f, 0.f, 0.f);
      if (node < NN) v = m4[idx];
      ms4[idx] = v;
    }
    const float4* w4 = (const float4*)W1;
    float4* Ws4 = (float4*)Ws;
#pragma unroll
    for (int i = 0; i < 4; ++i) Ws4[t + i * 256] = w4[t + i * 256];
  }
  __syncthreads();

  // GEMM1: t = relu(m @ W1)
  float acc[16];
#pragma unroll
  for (int j = 0; j < 16; ++j) acc[j] = 0.f;
  for (int k4 = 0; k4 < NH / 4; ++k4) {
    float w0 = Ws[(k4 * 4 + 0) * NH + ocol];
    float w1 = Ws[(k4 * 4 + 1) * NH + ocol];
    float w2 = Ws[(k4 * 4 + 2) * NH + ocol];
    float w3 = Ws[(k4 * 4 + 3) * NH + ocol];
#pragma unroll
    for (int j = 0; j < 16; ++j) {
      float4 mv = *(const float4*)&ms[(n0 + j) * NH + k4 * 4];
      acc[j] = fmaf(mv.w, w3, fmaf(mv.z, w2, fmaf(mv.y, w1, fmaf(mv.x, w0, acc[j]))));
    }
  }
#pragma unroll
  for (int j = 0; j < 16; ++j) ts[(n0 + j) * NH + ocol] = fmaxf(acc[j], 0.f);
  __syncthreads();
  {
    const float4* w4 = (const float4*)W2;
    float4* Ws4 = (float4*)Ws;
#pragma unroll
    for (int i = 0; i < 4; ++i) Ws4[t + i * 256] = w4[t + i * 256];
  }
  __syncthreads();

  // GEMM2: r = relu(t @ W2)
  float acc2[16];
#pragma unroll
  for (int j = 0; j < 16; ++j) acc2[j] = 0.f;
  for (int k4 = 0; k4 < NH / 4; ++k4) {
    float w0 = Ws[(k4 * 4 + 0) * NH + ocol];
    float w1 = Ws[(k4 * 4 + 1) * NH + ocol];
    float w2 = Ws[(k4 * 4 + 2) * NH + ocol];
    float w3 = Ws[(k4 * 4 + 3) * NH + ocol];
#pragma unroll
    for (int j = 0; j < 16; ++j) {
      float4 mv = *(const float4*)&ts[(n0 + j) * NH + k4 * 4];
      acc2[j] = fmaf(mv.w, w3, fmaf(mv.z, w2, fmaf(mv.y, w1, fmaf(mv.x, w0, acc2[j]))));
    }
  }
  float ls = 0.f, lss = 0.f;
#pragma unroll
  for (int j = 0; j < 16; ++j) {
    float v = fmaxf(acc2[j], 0.f);  // zero-staged OOB rows give exactly 0 -> safe for stats
    acc2[j] = v;
    ls += v;
    lss += v * v;
  }
  float* red = ms;  // ms no longer needed; [2][4][64]
  red[(t >> 6) * 64 + ocol] = ls;
  red[256 + (t >> 6) * 64 + ocol] = lss;
  __syncthreads();
  if (t < 64) {
    float s = red[t] + red[64 + t] + red[128 + t] + red[192 + t];
    float ss = red[256 + t] + red[320 + t] + red[384 + t] + red[448 + t];
    atomicAdd(&partials[t], s);
    atomicAdd(&partials[64 + t], ss);
  }
#pragma unroll
  for (int j = 0; j < 16; ++j) {
    int node = n0base + n0 + j;
    if (node < NN) r[(size_t)node * NH + ocol] = acc2[j];
  }
}

// ---------------- BN finalize + apply ----------------

__global__ void k_fin(float* __restrict__ partials, const float* __restrict__ gamma,
                      const float* __restrict__ beta, float* __restrict__ scsh) {
  int t = threadIdx.x;
  if (t < 64) {
    float s = partials[t], ss = partials[64 + t];
    float invn = 1.f / (float)NN;
    float mu = s * invn;
    float var = ss * invn - mu * mu;
    var = fmaxf(var, 0.f);
    float inv = rsqrtf(var + BN_EPS);
    float scale = gamma[t] * inv;
    scsh[t] = scale;
    scsh[64 + t] = beta[t] - mu * scale;
    partials[t] = 0.f;       // re-zero for next use
    partials[64 + t] = 0.f;
  }
}

__global__ void k_apply(const float* __restrict__ z, const float* __restrict__ scsh,
                        float* __restrict__ out) {
  int i = blockIdx.x * 256 + threadIdx.x;  // float4 index
  if (i < NN * (NH / 4)) {
    int c0 = (i * 4) & 63;
    float4 v = ((const float4*)z)[i];
    float4 o;
    o.x = v.x * scsh[c0 + 0] + scsh[64 + c0 + 0];
    o.y = v.y * scsh[c0 + 1] + scsh[64 + c0 + 1];
    o.z = v.z * scsh[c0 + 2] + scsh[64 + c0 + 2];
    o.w = v.w * scsh[c0 + 3] + scsh[64 + c0 + 3];
    ((float4*)out)[i] = o;
  }
}

// ---------------- launch ----------------

extern "C" void kernel_launch(void* const* d_in, const int* in_sizes, int n_in,
                              void* d_out, int out_size, void* d_ws, size_t ws_size,
                              hipStream_t stream) {
  (void)in_sizes; (void)n_in; (void)out_size; (void)ws_size;
  const float* x      = (const float*)d_in[0];
  const int*   ei     = (const int*)d_in[1];
  const float* Wt     = (const float*)d_in[2];
  const float* bt     = (const float*)d_in[3];
  const float* gt     = (const float*)d_in[4];
  const float* bet    = (const float*)d_in[5];
  const float* Ws1    = (const float*)d_in[6];
  const float* Ws2    = (const float*)d_in[7];
  const float* gammas = (const float*)d_in[8];
  const float* betas  = (const float*)d_in[9];

  const int* esrc = ei;
  const int* edst = ei + NE;

  float* h        = (float*)d_ws;                       // 3.2M floats
  float* mbuf     = h + (size_t)NN * NH;                // 3.2M floats
  int*   counts   = (int*)(mbuf + (size_t)NN * NH);     // 50000
  int*   rowptr   = counts + NN;                        // 50001
  int*   pos      = rowptr + NN + 1;                    // 50000
  int*   ebuf     = pos + NN;                           // 800000
  float* partials = (float*)(ebuf + NE);                // 128
  float* scsh     = partials + 128;                     // 128

  // CSR build (by dst)
  k_zero<<<(NN + 255) / 256, 256, 0, stream>>>(counts, partials);
  k_count<<<(NE + 255) / 256, 256, 0, stream>>>(edst, counts);
  k_scan<<<1, 1024, 0, stream>>>(counts, rowptr, pos);
  k_bucket<<<(NE + 255) / 256, 256, 0, stream>>>(esrc, edst, pos, ebuf);

  // input transform + BN
  k_in<<<(NN + 63) / 64, 256, 0, stream>>>(x, Wt, bt, mbuf, partials);
  k_fin<<<1, 64, 0, stream>>>(partials, gt, bet, scsh);
  k_apply<<<(NN * (NH / 4) + 255) / 256, 256, 0, stream>>>(mbuf, scsh, h);

  // 3 GIN layers
  for (int i = 0; i < 3; ++i) {
    k_agg<<<(NN + 3) / 4, 256, 0, stream>>>(h, rowptr, ebuf, mbuf);
    k_mlp<<<(NN + 63) / 64, 256, 0, stream>>>(mbuf, Ws1 + i * NH * NH, Ws2 + i * NH * NH,
                                              mbuf, partials);
    k_fin<<<1, 64, 0, stream>>>(partials, gammas + i * NH, betas + i * NH, scsh);
    float* outp = (i == 2) ? (float*)d_out : h;
    k_apply<<<(NN * (NH / 4) + 255) / 256, 256, 0, stream>>>(mbuf, scsh, outp);
  }
}

// Round 2
// 411.925 us; speedup vs baseline: 1.5730x; 1.5730x over previous
//
#include <hip/hip_runtime.h>

#define NN 50000
#define NE 800000
#define NF 128
#define NH 64
#define BN_EPS 1e-5f
#define SCAN_B 196  // ceil(NN/256)

// ---------------- zero: counts + all 4 BN-partials segments ----------------

__global__ void k_zero(int* __restrict__ counts, float* __restrict__ partials) {
  int i = blockIdx.x * 256 + threadIdx.x;
  if (i < NN) counts[i] = 0;
  if (i < 512) partials[i] = 0.f;
}

__global__ void k_count(const int* __restrict__ dst, int* __restrict__ counts) {
  int e = blockIdx.x * 256 + threadIdx.x;
  if (e < NE) atomicAdd(&counts[dst[e]], 1);
}

// ---------------- parallel 3-phase exclusive scan ----------------

__global__ __launch_bounds__(256) void k_scan_up(const int* __restrict__ counts,
                                                 int* __restrict__ blocksums) {
  __shared__ int red[256];
  int t = threadIdx.x, b = blockIdx.x;
  int i = b * 256 + t;
  red[t] = (i < NN) ? counts[i] : 0;
  __syncthreads();
  for (int off = 128; off > 0; off >>= 1) {
    if (t < off) red[t] += red[t + off];
    __syncthreads();
  }
  if (t == 0) blocksums[b] = red[0];
}

__global__ __launch_bounds__(256) void k_scan_mid(const int* __restrict__ blocksums,
                                                  int* __restrict__ blockoff,
                                                  int* __restrict__ rowptr) {
  __shared__ int ls[256];
  int t = threadIdx.x;
  int v = (t < SCAN_B) ? blocksums[t] : 0;
  ls[t] = v;
  __syncthreads();
  for (int off = 1; off < 256; off <<= 1) {
    int u = (t >= off) ? ls[t - off] : 0;
    __syncthreads();
    ls[t] += u;
    __syncthreads();
  }
  if (t < SCAN_B) blockoff[t] = ls[t] - v;  // exclusive block offsets
  if (t == SCAN_B - 1) rowptr[NN] = ls[t];
}

__global__ __launch_bounds__(256) void k_scan_down(const int* __restrict__ counts,
                                                   const int* __restrict__ blockoff,
                                                   int* __restrict__ rowptr,
                                                   int* __restrict__ pos) {
  __shared__ int ls[256];
  int t = threadIdx.x, b = blockIdx.x;
  int i = b * 256 + t;
  int v = (i < NN) ? counts[i] : 0;
  ls[t] = v;
  __syncthreads();
  for (int off = 1; off < 256; off <<= 1) {
    int u = (t >= off) ? ls[t - off] : 0;
    __syncthreads();
    ls[t] += u;
    __syncthreads();
  }
  if (i < NN) {
    int excl = blockoff[b] + ls[t] - v;
    rowptr[i] = excl;
    pos[i] = excl;
  }
}

__global__ void k_bucket(const int* __restrict__ src, const int* __restrict__ dst,
                         int* __restrict__ pos, int* __restrict__ ebuf) {
  int e = blockIdx.x * 256 + threadIdx.x;
  if (e < NE) {
    int d = dst[e];
    int idx = atomicAdd(&pos[d], 1);
    ebuf[idx] = src[e];
  }
}

// ------ aggregation with fused BN affine:
// m[i] = scale .* (z[i] + sum_j z[j])  +  (deg_i + 1) * shift ------

__global__ __launch_bounds__(256) void k_agg(const float* __restrict__ z,
                                             const int* __restrict__ rowptr,
                                             const int* __restrict__ ebuf,
                                             const float* __restrict__ part,
                                             const float* __restrict__ gamma,
                                             const float* __restrict__ beta,
                                             float* __restrict__ m) {
  __shared__ float sc[64], sh[64];
  int t = threadIdx.x;
  if (t < 64) {
    float s = part[t], ss = part[64 + t];
    float invn = 1.f / (float)NN;
    float mu = s * invn;
    float var = fmaxf(ss * invn - mu * mu, 0.f);
    float inv = rsqrtf(var + BN_EPS);
    float scale = gamma[t] * inv;
    sc[t] = scale;
    sh[t] = beta[t] - mu * scale;
  }
  __syncthreads();
  int node = blockIdx.x * 4 + (t >> 6);
  int lane = t & 63;
  int beg = rowptr[node], end = rowptr[node + 1];
  float acc = z[(size_t)node * NH + lane];
  int j = beg;
  for (; j + 3 < end; j += 4) {
    int s0 = ebuf[j], s1 = ebuf[j + 1], s2 = ebuf[j + 2], s3 = ebuf[j + 3];
    float a0 = z[(size_t)s0 * NH + lane];
    float a1 = z[(size_t)s1 * NH + lane];
    float a2 = z[(size_t)s2 * NH + lane];
    float a3 = z[(size_t)s3 * NH + lane];
    acc += (a0 + a1) + (a2 + a3);
  }
  for (; j < end; ++j) acc += z[(size_t)ebuf[j] * NH + lane];
  float deg1 = (float)(end - beg + 1);
  m[(size_t)node * NH + lane] = sc[lane] * acc + deg1 * sh[lane];
}

// ---------------- input transform: z = x @ Wt + bt, + BN partials ----------------

__global__ __launch_bounds__(256) void k_in(const float* __restrict__ x,
                                            const float* __restrict__ Wt,
                                            const float* __restrict__ bt,
                                            float* __restrict__ z,
                                            float* __restrict__ partials) {
  __shared__ float xs[64 * NF];  // 32 KB
  __shared__ float Ws[NF * NH];  // 32 KB
  int t = threadIdx.x;
  int n0base = blockIdx.x * 64;
  int ocol = t & 63;
  int n0 = (t >> 6) * 16;
  {
    const float4* x4 = (const float4*)(x + (size_t)n0base * NF);
    float4* xs4 = (float4*)xs;
#pragma unroll
    for (int i = 0; i < 8; ++i) {
      int idx = t + i * 256;            // float4 index 0..2047
      int node = n0base + (idx >> 5);   // 32 float4 per node row
      float4 v = make_float4(0.f, 0.f, 0.f, 0.f);
      if (node < NN) v = x4[idx];
      xs4[idx] = v;
    }
    const float4* w4 = (const float4*)Wt;
    float4* Ws4 = (float4*)Ws;
#pragma unroll
    for (int i = 0; i < 8; ++i) Ws4[t + i * 256] = w4[t + i * 256];
  }
  __syncthreads();

  float acc[16];
#pragma unroll
  for (int j = 0; j < 16; ++j) acc[j] = 0.f;
  for (int k4 = 0; k4 < NF / 4; ++k4) {
    float w0 = Ws[(k4 * 4 + 0) * NH + ocol];
    float w1 = Ws[(k4 * 4 + 1) * NH + ocol];
    float w2 = Ws[(k4 * 4 + 2) * NH + ocol];
    float w3 = Ws[(k4 * 4 + 3) * NH + ocol];
#pragma unroll
    for (int j = 0; j < 16; ++j) {
      float4 mv = *(const float4*)&xs[(n0 + j) * NF + k4 * 4];
      acc[j] = fmaf(mv.w, w3, fmaf(mv.z, w2, fmaf(mv.y, w1, fmaf(mv.x, w0, acc[j]))));
    }
  }
  float b = bt[ocol];
  float ls = 0.f, lss = 0.f;
#pragma unroll
  for (int j = 0; j < 16; ++j) {
    float v = acc[j] + b;
    acc[j] = v;
    if (n0base + n0 + j < NN) { ls += v; lss += v * v; }
  }
  __syncthreads();  // everyone done reading Ws
  float* red = Ws;  // reuse as [2][4][64]
  red[(t >> 6) * 64 + ocol] = ls;
  red[256 + (t >> 6) * 64 + ocol] = lss;
  __syncthreads();
  if (t < 64) {
    float s = red[t] + red[64 + t] + red[128 + t] + red[192 + t];
    float ss = red[256 + t] + red[320 + t] + red[384 + t] + red[448 + t];
    atomicAdd(&partials[t], s);
    atomicAdd(&partials[64 + t], ss);
  }
#pragma unroll
  for (int j = 0; j < 16; ++j) {
    int node = n0base + n0 + j;
    if (node < NN) z[(size_t)node * NH + ocol] = acc[j];
  }
}

// ---------------- MLP: r = relu(relu(m@W1)@W2), + BN partials ----------------

__global__ __launch_bounds__(256) void k_mlp(const float* __restrict__ m,
                                             const float* __restrict__ W1,
                                             const float* __restrict__ W2,
                                             float* __restrict__ r,
                                             float* __restrict__ partials) {
  __shared__ float ms[64 * NH];  // 16 KB
  __shared__ float ts[64 * NH];  // 16 KB
  __shared__ float Ws[NH * NH];  // 16 KB
  int t = threadIdx.x;
  int n0base = blockIdx.x * 64;
  int ocol = t & 63;
  int n0 = (t >> 6) * 16;
  {
    const float4* m4 = (const float4*)(m + (size_t)n0base * NH);
    float4* ms4 = (float4*)ms;
#pragma unroll
    for (int i = 0; i < 4; ++i) {
      int idx = t + i * 256;            // float4 index 0..1023
      int node = n0base + (idx >> 4);   // 16 float4 per node row
      float4 v = make_float4(0.f, 0.f, 0.f, 0.f);
      if (node < NN) v = m4[idx];
      ms4[idx] = v;
    }
    const float4* w4 = (const float4*)W1;
    float4* Ws4 = (float4*)Ws;
#pragma unroll
    for (int i = 0; i < 4; ++i) Ws4[t + i * 256] = w4[t + i * 256];
  }
  __syncthreads();

  // GEMM1: t = relu(m @ W1)
  float acc[16];
#pragma unroll
  for (int j = 0; j < 16; ++j) acc[j] = 0.f;
  for (int k4 = 0; k4 < NH / 4; ++k4) {
    float w0 = Ws[(k4 * 4 + 0) * NH + ocol];
    float w1 = Ws[(k4 * 4 + 1) * NH + ocol];
    float w2 = Ws[(k4 * 4 + 2) * NH + ocol];
    float w3 = Ws[(k4 * 4 + 3) * NH + ocol];
#pragma unroll
    for (int j = 0; j < 16; ++j) {
      float4 mv = *(const float4*)&ms[(n0 + j) * NH + k4 * 4];
      acc[j] = fmaf(mv.w, w3, fmaf(mv.z, w2, fmaf(mv.y, w1, fmaf(mv.x, w0, acc[j]))));
    }
  }
#pragma unroll
  for (int j = 0; j < 16; ++j) ts[(n0 + j) * NH + ocol] = fmaxf(acc[j], 0.f);
  __syncthreads();
  {
    const float4* w4 = (const float4*)W2;
    float4* Ws4 = (float4*)Ws;
#pragma unroll
    for (int i = 0; i < 4; ++i) Ws4[t + i * 256] = w4[t + i * 256];
  }
  __syncthreads();

  // GEMM2: r = relu(t @ W2)
  float acc2[16];
#pragma unroll
  for (int j = 0; j < 16; ++j) acc2[j] = 0.f;
  for (int k4 = 0; k4 < NH / 4; ++k4) {
    float w0 = Ws[(k4 * 4 + 0) * NH + ocol];
    float w1 = Ws[(k4 * 4 + 1) * NH + ocol];
    float w2 = Ws[(k4 * 4 + 2) * NH + ocol];
    float w3 = Ws[(k4 * 4 + 3) * NH + ocol];
#pragma unroll
    for (int j = 0; j < 16; ++j) {
      float4 mv = *(const float4*)&ts[(n0 + j) * NH + k4 * 4];
      acc2[j] = fmaf(mv.w, w3, fmaf(mv.z, w2, fmaf(mv.y, w1, fmaf(mv.x, w0, acc2[j]))));
    }
  }
  float ls = 0.f, lss = 0.f;
#pragma unroll
  for (int j = 0; j < 16; ++j) {
    float v = fmaxf(acc2[j], 0.f);  // zero-staged OOB rows give exactly 0 -> safe for stats
    acc2[j] = v;
    ls += v;
    lss += v * v;
  }
  float* red = ms;  // ms no longer needed; [2][4][64]
  red[(t >> 6) * 64 + ocol] = ls;
  red[256 + (t >> 6) * 64 + ocol] = lss;
  __syncthreads();
  if (t < 64) {
    float s = red[t] + red[64 + t] + red[128 + t] + red[192 + t];
    float ss = red[256 + t] + red[320 + t] + red[384 + t] + red[448 + t];
    atomicAdd(&partials[t], s);
    atomicAdd(&partials[64 + t], ss);
  }
#pragma unroll
  for (int j = 0; j < 16; ++j) {
    int node = n0base + n0 + j;
    if (node < NN) r[(size_t)node * NH + ocol] = acc2[j];
  }
}

// ---------------- final BN apply (finalize fused) ----------------

__global__ __launch_bounds__(256) void k_apply(const float* __restrict__ r,
                                               const float* __restrict__ part,
                                               const float* __restrict__ gamma,
                                               const float* __restrict__ beta,
                                               float* __restrict__ out) {
  __shared__ float sc[64], sh[64];
  int t = threadIdx.x;
  if (t < 64) {
    float s = part[t], ss = part[64 + t];
    float invn = 1.f / (float)NN;
    float mu = s * invn;
    float var = fmaxf(ss * invn - mu * mu, 0.f);
    float inv = rsqrtf(var + BN_EPS);
    float scale = gamma[t] * inv;
    sc[t] = scale;
    sh[t] = beta[t] - mu * scale;
  }
  __syncthreads();
  int i = blockIdx.x * 256 + t;  // float4 index
  if (i < NN * (NH / 4)) {
    int c0 = (i * 4) & 63;
    float4 v = ((const float4*)r)[i];
    float4 o;
    o.x = v.x * sc[c0 + 0] + sh[c0 + 0];
    o.y = v.y * sc[c0 + 1] + sh[c0 + 1];
    o.z = v.z * sc[c0 + 2] + sh[c0 + 2];
    o.w = v.w * sc[c0 + 3] + sh[c0 + 3];
    ((float4*)out)[i] = o;
  }
}

// ---------------- launch ----------------

extern "C" void kernel_launch(void* const* d_in, const int* in_sizes, int n_in,
                              void* d_out, int out_size, void* d_ws, size_t ws_size,
                              hipStream_t stream) {
  (void)in_sizes; (void)n_in; (void)out_size; (void)ws_size;
  const float* x      = (const float*)d_in[0];
  const int*   ei     = (const int*)d_in[1];
  const float* Wt     = (const float*)d_in[2];
  const float* bt     = (const float*)d_in[3];
  const float* gt     = (const float*)d_in[4];
  const float* bet    = (const float*)d_in[5];
  const float* Ws1    = (const float*)d_in[6];
  const float* Ws2    = (const float*)d_in[7];
  const float* gammas = (const float*)d_in[8];
  const float* betas  = (const float*)d_in[9];

  const int* esrc = ei;
  const int* edst = ei + NE;

  float* bufA      = (float*)d_ws;                      // 3.2M floats
  float* bufB      = bufA + (size_t)NN * NH;            // 3.2M floats
  int*   counts    = (int*)(bufB + (size_t)NN * NH);    // 50000
  int*   rowptr    = counts + NN;                       // 50001
  int*   pos       = rowptr + NN + 1;                   // 50000
  int*   ebuf      = pos + NN;                          // 800000
  int*   blocksums = ebuf + NE;                         // 256
  int*   blockoff  = blocksums + 256;                   // 256
  float* partials  = (float*)(blockoff + 256);          // 4 segments x 128

  // CSR build (by dst)
  k_zero<<<SCAN_B, 256, 0, stream>>>(counts, partials);
  k_count<<<NE / 256, 256, 0, stream>>>(edst, counts);
  k_scan_up<<<SCAN_B, 256, 0, stream>>>(counts, blocksums);
  k_scan_mid<<<1, 256, 0, stream>>>(blocksums, blockoff, rowptr);
  k_scan_down<<<SCAN_B, 256, 0, stream>>>(counts, blockoff, rowptr, pos);
  k_bucket<<<NE / 256, 256, 0, stream>>>(esrc, edst, pos, ebuf);

  // input transform (raw z + stats -> seg 0)
  k_in<<<(NN + 63) / 64, 256, 0, stream>>>(x, Wt, bt, bufA, partials);

  // L0: agg(BN0 fused) A->B ; mlp B->B (stats -> seg1)
  k_agg<<<NN / 4, 256, 0, stream>>>(bufA, rowptr, ebuf, partials, gt, bet, bufB);
  k_mlp<<<(NN + 63) / 64, 256, 0, stream>>>(bufB, Ws1, Ws2, bufB, partials + 128);

  // L1: agg(BN1 fused) B->A ; mlp A->A (stats -> seg2)
  k_agg<<<NN / 4, 256, 0, stream>>>(bufB, rowptr, ebuf, partials + 128, gammas, betas, bufA);
  k_mlp<<<(NN + 63) / 64, 256, 0, stream>>>(bufA, Ws1 + NH * NH, Ws2 + NH * NH, bufA,
                                            partials + 256);

  // L2: agg(BN2 fused) A->B ; mlp B->B (stats -> seg3)
  k_agg<<<NN / 4, 256, 0, stream>>>(bufA, rowptr, ebuf, partials + 256, gammas + NH,
                                    betas + NH, bufB);
  k_mlp<<<(NN + 63) / 64, 256, 0, stream>>>(bufB, Ws1 + 2 * NH * NH, Ws2 + 2 * NH * NH, bufB,
                                            partials + 384);

  // final BN apply -> d_out
  k_apply<<<(NN * (NH / 4) + 255) / 256, 256, 0, stream>>>(bufB, partials + 384,
                                                           gammas + 2 * NH, betas + 2 * NH,
                                                           (float*)d_out);
}

// Round 4
// 281.655 us; speedup vs baseline: 2.3006x; 1.4625x over previous
//
#include <hip/hip_runtime.h>

#define NN 50000
#define NE 800000
#define NF 128
#define NH 64
#define BN_EPS 1e-5f
#define SCAN_B 196   // ceil(NN/256)
#define NCOPY 16
#define SEG (NCOPY * 128)

typedef __bf16 bf16x8 __attribute__((ext_vector_type(8)));
typedef float f32x4 __attribute__((ext_vector_type(4)));
#define MFMA __builtin_amdgcn_mfma_f32_16x16x32_bf16

__device__ inline unsigned short bf_hi(float f) {
  unsigned u = __float_as_uint(f);
  unsigned r = u + 0x7FFFu + ((u >> 16) & 1u);
  return (unsigned short)(r >> 16);
}
__device__ inline float bf_to_f(unsigned short s) {
  return __uint_as_float(((unsigned)s) << 16);
}

union BF8 { bf16x8 v; unsigned short s[8]; };

// Build hi/lo bf16x8 A-fragments from 8 consecutive fp32 (zero if !valid).
__device__ inline void make_ab(const float* p, bool valid, bf16x8& hi, bf16x8& lo) {
  BF8 H, L;
  if (valid) {
    float4 f0 = *(const float4*)p;
    float4 f1 = *(const float4*)(p + 4);
    float ff[8] = {f0.x, f0.y, f0.z, f0.w, f1.x, f1.y, f1.z, f1.w};
#pragma unroll
    for (int e = 0; e < 8; ++e) {
      unsigned short h = bf_hi(ff[e]);
      H.s[e] = h;
      L.s[e] = bf_hi(ff[e] - bf_to_f(h));
    }
  } else {
#pragma unroll
    for (int e = 0; e < 8; ++e) { H.s[e] = 0; L.s[e] = 0; }
  }
  hi = H.v; lo = L.v;
}

// Stage W[K][64] fp32 -> LDS bf16 hi/lo planes in B-fragment layout:
// frag (ks, ct) holds 512 bf16; lane (kg,c15) reads 8 contiguous at (kg*16+c15)*8.
// Slot convention: element e of lane-group kg holds k = ks*32 + kg*8 + e (same as A).
template <int K>
__device__ inline void stage_w(const float* __restrict__ W,
                               unsigned short* __restrict__ wh,
                               unsigned short* __restrict__ wl) {
  int t = threadIdx.x;
#pragma unroll
  for (int i = 0; i < K * 64 / 256; ++i) {
    int idx = t + i * 256;
    int k = idx >> 6, c = idx & 63;
    float f = W[idx];
    unsigned short h = bf_hi(f);
    unsigned short l = bf_hi(f - bf_to_f(h));
    int off = ((k >> 5) * 4 + (c >> 4)) * 512 + (((k >> 3) & 3) * 16 + (c & 15)) * 8 + (k & 7);
    wh[off] = h;
    wl[off] = l;
  }
}

// ---------------- zero: counts + all BN-partials copies ----------------

__global__ void k_zero(int* __restrict__ counts, float* __restrict__ partials) {
  int i = blockIdx.x * 256 + threadIdx.x;
  if (i < NN) counts[i] = 0;
  if (i < 4 * SEG) partials[i] = 0.f;
}

__global__ void k_count(const int* __restrict__ dst, int* __restrict__ counts) {
  int e = blockIdx.x * 256 + threadIdx.x;
  if (e < NE) atomicAdd(&counts[dst[e]], 1);
}

// ---------------- parallel 3-phase exclusive scan ----------------

__global__ __launch_bounds__(256) void k_scan_up(const int* __restrict__ counts,
                                                 int* __restrict__ blocksums) {
  __shared__ int red[256];
  int t = threadIdx.x, b = blockIdx.x;
  int i = b * 256 + t;
  red[t] = (i < NN) ? counts[i] : 0;
  __syncthreads();
  for (int off = 128; off > 0; off >>= 1) {
    if (t < off) red[t] += red[t + off];
    __syncthreads();
  }
  if (t == 0) blocksums[b] = red[0];
}

__global__ __launch_bounds__(256) void k_scan_mid(const int* __restrict__ blocksums,
                                                  int* __restrict__ blockoff,
                                                  int* __restrict__ rowptr) {
  __shared__ int ls[256];
  int t = threadIdx.x;
  int v = (t < SCAN_B) ? blocksums[t] : 0;
  ls[t] = v;
  __syncthreads();
  for (int off = 1; off < 256; off <<= 1) {
    int u = (t >= off) ? ls[t - off] : 0;
    __syncthreads();
    ls[t] += u;
    __syncthreads();
  }
  if (t < SCAN_B) blockoff[t] = ls[t] - v;
  if (t == SCAN_B - 1) rowptr[NN] = ls[t];
}

__global__ __launch_bounds__(256) void k_scan_down(const int* __restrict__ counts,
                                                   const int* __restrict__ blockoff,
                                                   int* __restrict__ rowptr,
                                                   int* __restrict__ pos) {
  __shared__ int ls[256];
  int t = threadIdx.x, b = blockIdx.x;
  int i = b * 256 + t;
  int v = (i < NN) ? counts[i] : 0;
  ls[t] = v;
  __syncthreads();
  for (int off = 1; off < 256; off <<= 1) {
    int u = (t >= off) ? ls[t - off] : 0;
    __syncthreads();
    ls[t] += u;
    __syncthreads();
  }
  if (i < NN) {
    int excl = blockoff[b] + ls[t] - v;
    rowptr[i] = excl;
    pos[i] = excl;
  }
}

__global__ void k_bucket(const int* __restrict__ src, const int* __restrict__ dst,
                         int* __restrict__ pos, int* __restrict__ ebuf) {
  int e = blockIdx.x * 256 + threadIdx.x;
  if (e < NE) {
    int d = dst[e];
    int idx = atomicAdd(&pos[d], 1);
    ebuf[idx] = src[e];
  }
}

// ------ aggregation with fused BN affine:
// m[i] = scale .* (z[i] + sum_j z[j]) + (deg_i + 1) * shift ------

__global__ __launch_bounds__(256) void k_agg(const float* __restrict__ z,
                                             const int* __restrict__ rowptr,
                                             const int* __restrict__ ebuf,
                                             const float* __restrict__ part,
                                             const float* __restrict__ gamma,
                                             const float* __restrict__ beta,
                                             float* __restrict__ m) {
  __shared__ float sc[64], sh[64];
  int t = threadIdx.x;
  if (t < 64) {
    float s = 0.f, ss = 0.f;
#pragma unroll
    for (int c = 0; c < NCOPY; ++c) { s += part[c * 128 + t]; ss += part[c * 128 + 64 + t]; }
    float invn = 1.f / (float)NN;
    float mu = s * invn;
    float var = fmaxf(ss * invn - mu * mu, 0.f);
    float inv = rsqrtf(var + BN_EPS);
    float scale = gamma[t] * inv;
    sc[t] = scale;
    sh[t] = beta[t] - mu * scale;
  }
  __syncthreads();
  int node = blockIdx.x * 4 + (t >> 6);
  int lane = t & 63;
  int beg = rowptr[node], end = rowptr[node + 1];
  float acc = z[(size_t)node * NH + lane];
  int j = beg;
  for (; j + 3 < end; j += 4) {
    int s0 = ebuf[j], s1 = ebuf[j + 1], s2 = ebuf[j + 2], s3 = ebuf[j + 3];
    float a0 = z[(size_t)s0 * NH + lane];
    float a1 = z[(size_t)s1 * NH + lane];
    float a2 = z[(size_t)s2 * NH + lane];
    float a3 = z[(size_t)s3 * NH + lane];
    acc += (a0 + a1) + (a2 + a3);
  }
  for (; j < end; ++j) acc += z[(size_t)ebuf[j] * NH + lane];
  float deg1 = (float)(end - beg + 1);
  m[(size_t)node * NH + lane] = sc[lane] * acc + deg1 * sh[lane];
}

// ---------------- input transform (MFMA): z = x @ Wt + bt, + BN partials ----------------

__global__ __launch_bounds__(256) void k_in(const float* __restrict__ x,
                                            const float* __restrict__ Wt,
                                            const float* __restrict__ bt,
                                            float* __restrict__ z,
                                            float* __restrict__ part_out) {
  __shared__ unsigned short wh[8192], wl[8192];  // 32 KB
  __shared__ float reds[16][64], redss[16][64];  // 8 KB
  int t = threadIdx.x;
  stage_w<NF>(Wt, wh, wl);
  int wv = t >> 6, lane = t & 63;
  int c15 = lane & 15, kg = lane >> 4;
  int n0 = blockIdx.x * 64 + wv * 16;
  int arow = n0 + c15;

  bf16x8 ah[4], al[4];
  const float* ap = x + (size_t)arow * NF + kg * 8;
#pragma unroll
  for (int ks = 0; ks < 4; ++ks) make_ab(ap + ks * 32, arow < NN, ah[ks], al[ks]);
  __syncthreads();

  const bf16x8* bh = (const bf16x8*)wh;
  const bf16x8* bl = (const bf16x8*)wl;
  float sAcc[4], ssAcc[4];
#pragma unroll
  for (int ct = 0; ct < 4; ++ct) {
    f32x4 acc = {0.f, 0.f, 0.f, 0.f};
#pragma unroll
    for (int ks = 0; ks < 4; ++ks) {
      bf16x8 wbh = bh[(ks * 4 + ct) * 64 + kg * 16 + c15];
      bf16x8 wbl = bl[(ks * 4 + ct) * 64 + kg * 16 + c15];
      acc = MFMA(al[ks], wbh, acc, 0, 0, 0);
      acc = MFMA(ah[ks], wbl, acc, 0, 0, 0);
      acc = MFMA(ah[ks], wbh, acc, 0, 0, 0);
    }
    float b = bt[ct * 16 + c15];
    float s = 0.f, ss = 0.f;
#pragma unroll
    for (int g = 0; g < 4; ++g) {
      int row = n0 + kg * 4 + g;
      float v = acc[g] + b;
      if (row < NN) {
        z[(size_t)row * NH + ct * 16 + c15] = v;
        s += v;
        ss += v * v;
      }
    }
    sAcc[ct] = s;
    ssAcc[ct] = ss;
  }
  // full 64-column coverage of reds/redss BEFORE the reduction reads them
#pragma unroll
  for (int ct = 0; ct < 4; ++ct) {
    reds[wv * 4 + kg][ct * 16 + c15] = sAcc[ct];
    redss[wv * 4 + kg][ct * 16 + c15] = ssAcc[ct];
  }
  __syncthreads();
  if (t < 64) {
    float s2 = 0.f, ss2 = 0.f;
#pragma unroll
    for (int i = 0; i < 16; ++i) { s2 += reds[i][t]; ss2 += redss[i][t]; }
    int cp = (blockIdx.x & (NCOPY - 1)) * 128;
    atomicAdd(&part_out[cp + t], s2);
    atomicAdd(&part_out[cp + 64 + t], ss2);
  }
}

// ---------------- MLP (MFMA): r = relu(relu(m@W1)@W2), + BN partials ----------------

__global__ __launch_bounds__(256) void k_mlp(const float* __restrict__ m,
                                             const float* __restrict__ W1,
                                             const float* __restrict__ W2,
                                             float* __restrict__ r,
                                             float* __restrict__ part_out) {
  __shared__ unsigned short w1h[4096], w1l[4096], w2h[4096], w2l[4096];  // 32 KB
  __shared__ unsigned short tls[4][2][16][72];                           // 18.4 KB
  __shared__ float reds[16][64], redss[16][64];                          // 8 KB
  int t = threadIdx.x;
  stage_w<NH>(W1, w1h, w1l);
  stage_w<NH>(W2, w2h, w2l);
  int wv = t >> 6, lane = t & 63;
  int c15 = lane & 15, kg = lane >> 4;
  int n0 = blockIdx.x * 64 + wv * 16;
  int arow = n0 + c15;

  bf16x8 ah[2], al[2];
  const float* ap = m + (size_t)arow * NH + kg * 8;
  make_ab(ap, arow < NN, ah[0], al[0]);
  make_ab(ap + 32, arow < NN, ah[1], al[1]);
  __syncthreads();

  // GEMM1: t = relu(m @ W1)
  const bf16x8* b1h = (const bf16x8*)w1h;
  const bf16x8* b1l = (const bf16x8*)w1l;
  float tv[4][4];
#pragma unroll
  for (int ct = 0; ct < 4; ++ct) {
    f32x4 acc = {0.f, 0.f, 0.f, 0.f};
#pragma unroll
    for (int ks = 0; ks < 2; ++ks) {
      bf16x8 wbh = b1h[(ks * 4 + ct) * 64 + kg * 16 + c15];
      bf16x8 wbl = b1l[(ks * 4 + ct) * 64 + kg * 16 + c15];
      acc = MFMA(al[ks], wbh, acc, 0, 0, 0);
      acc = MFMA(ah[ks], wbl, acc, 0, 0, 0);
      acc = MFMA(ah[ks], wbh, acc, 0, 0, 0);
    }
#pragma unroll
    for (int g = 0; g < 4; ++g) tv[ct][g] = fmaxf(acc[g], 0.f);
  }
  // write t (hi/lo bf16) to per-wave LDS tile, row=node-in-tile, col=channel
#pragma unroll
  for (int ct = 0; ct < 4; ++ct)
#pragma unroll
    for (int g = 0; g < 4; ++g) {
      int rr = kg * 4 + g, cc = ct * 16 + c15;
      unsigned short h = bf_hi(tv[ct][g]);
      tls[wv][0][rr][cc] = h;
      tls[wv][1][rr][cc] = bf_hi(tv[ct][g] - bf_to_f(h));
    }
  __syncthreads();

  // GEMM2: r = relu(t @ W2)
  bf16x8 a2h[2], a2l[2];
#pragma unroll
  for (int ks = 0; ks < 2; ++ks) {
    a2h[ks] = *(const bf16x8*)&tls[wv][0][c15][ks * 32 + kg * 8];
    a2l[ks] = *(const bf16x8*)&tls[wv][1][c15][ks * 32 + kg * 8];
  }
  const bf16x8* b2h = (const bf16x8*)w2h;
  const bf16x8* b2l = (const bf16x8*)w2l;
  float sAcc[4], ssAcc[4];
#pragma unroll
  for (int ct = 0; ct < 4; ++ct) {
    f32x4 acc = {0.f, 0.f, 0.f, 0.f};
#pragma unroll
    for (int ks = 0; ks < 2; ++ks) {
      bf16x8 wbh = b2h[(ks * 4 + ct) * 64 + kg * 16 + c15];
      bf16x8 wbl = b2l[(ks * 4 + ct) * 64 + kg * 16 + c15];
      acc = MFMA(a2l[ks], wbh, acc, 0, 0, 0);
      acc = MFMA(a2h[ks], wbl, acc, 0, 0, 0);
      acc = MFMA(a2h[ks], wbh, acc, 0, 0, 0);
    }
    float s = 0.f, ss = 0.f;
#pragma unroll
    for (int g = 0; g < 4; ++g) {
      float v = fmaxf(acc[g], 0.f);
      int row = n0 + kg * 4 + g;
      if (row < NN) r[(size_t)row * NH + ct * 16 + c15] = v;
      s += v;   // OOB rows give exactly 0 -> safe for stats
      ss += v * v;
    }
    sAcc[ct] = s;
    ssAcc[ct] = ss;
  }
  // full 64-column coverage of reds/redss BEFORE the reduction reads them
#pragma unroll
  for (int ct = 0; ct < 4; ++ct) {
    reds[wv * 4 + kg][ct * 16 + c15] = sAcc[ct];
    redss[wv * 4 + kg][ct * 16 + c15] = ssAcc[ct];
  }
  __syncthreads();
  if (t < 64) {
    float s2 = 0.f, ss2 = 0.f;
#pragma unroll
    for (int i = 0; i < 16; ++i) { s2 += reds[i][t]; ss2 += redss[i][t]; }
    int cp = (blockIdx.x & (NCOPY - 1)) * 128;
    atomicAdd(&part_out[cp + t], s2);
    atomicAdd(&part_out[cp + 64 + t], ss2);
  }
}

// ---------------- final BN apply (finalize fused) ----------------

__global__ __launch_bounds__(256) void k_apply(const float* __restrict__ r,
                                               const float* __restrict__ part,
                                               const float* __restrict__ gamma,
                                               const float* __restrict__ beta,
                                               float* __restrict__ out) {
  __shared__ float sc[64], sh[64];
  int t = threadIdx.x;
  if (t < 64) {
    float s = 0.f, ss = 0.f;
#pragma unroll
    for (int c = 0; c < NCOPY; ++c) { s += part[c * 128 + t]; ss += part[c * 128 + 64 + t]; }
    float invn = 1.f / (float)NN;
    float mu = s * invn;
    float var = fmaxf(ss * invn - mu * mu, 0.f);
    float inv = rsqrtf(var + BN_EPS);
    float scale = gamma[t] * inv;
    sc[t] = scale;
    sh[t] = beta[t] - mu * scale;
  }
  __syncthreads();
  int i = blockIdx.x * 256 + t;  // float4 index
  if (i < NN * (NH / 4)) {
    int c0 = (i * 4) & 63;
    float4 v = ((const float4*)r)[i];
    float4 o;
    o.x = v.x * sc[c0 + 0] + sh[c0 + 0];
    o.y = v.y * sc[c0 + 1] + sh[c0 + 1];
    o.z = v.z * sc[c0 + 2] + sh[c0 + 2];
    o.w = v.w * sc[c0 + 3] + sh[c0 + 3];
    ((float4*)out)[i] = o;
  }
}

// ---------------- launch ----------------

extern "C" void kernel_launch(void* const* d_in, const int* in_sizes, int n_in,
                              void* d_out, int out_size, void* d_ws, size_t ws_size,
                              hipStream_t stream) {
  (void)in_sizes; (void)n_in; (void)out_size; (void)ws_size;
  const float* x      = (const float*)d_in[0];
  const int*   ei     = (const int*)d_in[1];
  const float* Wt     = (const float*)d_in[2];
  const float* bt     = (const float*)d_in[3];
  const float* gt     = (const float*)d_in[4];
  const float* bet    = (const float*)d_in[5];
  const float* Ws1    = (const float*)d_in[6];
  const float* Ws2    = (const float*)d_in[7];
  const float* gammas = (const float*)d_in[8];
  const float* betas  = (const float*)d_in[9];

  const int* esrc = ei;
  const int* edst = ei + NE;

  float* bufA      = (float*)d_ws;
  float* bufB      = bufA + (size_t)NN * NH;
  int*   counts    = (int*)(bufB + (size_t)NN * NH);
  int*   rowptr    = counts + NN;
  int*   pos       = rowptr + NN + 1;
  int*   ebuf      = pos + NN;
  int*   blocksums = ebuf + NE;
  int*   blockoff  = blocksums + 256;
  float* partials  = (float*)(blockoff + 256);  // 4 segments x NCOPY x 128

  const int GB = (NN + 63) / 64;  // 782

  // CSR build (by dst)
  k_zero<<<SCAN_B, 256, 0, stream>>>(counts, partials);
  k_count<<<NE / 256, 256, 0, stream>>>(edst, counts);
  k_scan_up<<<SCAN_B, 256, 0, stream>>>(counts, blocksums);
  k_scan_mid<<<1, 256, 0, stream>>>(blocksums, blockoff, rowptr);
  k_scan_down<<<SCAN_B, 256, 0, stream>>>(counts, blockoff, rowptr, pos);
  k_bucket<<<NE / 256, 256, 0, stream>>>(esrc, edst, pos, ebuf);

  // input transform (raw z + stats -> seg 0)
  k_in<<<GB, 256, 0, stream>>>(x, Wt, bt, bufA, partials);

  // L0
  k_agg<<<NN / 4, 256, 0, stream>>>(bufA, rowptr, ebuf, partials, gt, bet, bufB);
  k_mlp<<<GB, 256, 0, stream>>>(bufB, Ws1, Ws2, bufB, partials + SEG);

  // L1
  k_agg<<<NN / 4, 256, 0, stream>>>(bufB, rowptr, ebuf, partials + SEG, gammas, betas, bufA);
  k_mlp<<<GB, 256, 0, stream>>>(bufA, Ws1 + NH * NH, Ws2 + NH * NH, bufA, partials + 2 * SEG);

  // L2
  k_agg<<<NN / 4, 256, 0, stream>>>(bufA, rowptr, ebuf, partials + 2 * SEG, gammas + NH,
                                    betas + NH, bufB);
  k_mlp<<<GB, 256, 0, stream>>>(bufB, Ws1 + 2 * NH * NH, Ws2 + 2 * NH * NH, bufB,
                                partials + 3 * SEG);

  // final BN apply -> d_out
  k_apply<<<(NN * (NH / 4) + 255) / 256, 256, 0, stream>>>(bufB, partials + 3 * SEG,
                                                           gammas + 2 * NH, betas + 2 * NH,
                                                           (float*)d_out);
}

// Round 5
// 224.672 us; speedup vs baseline: 2.8841x; 1.2536x over previous
//
#include <hip/hip_runtime.h>

#define NN 50000
#define NE 800000
#define NF 128
#define NH 64
#define BN_EPS 1e-5f
#define NB 196       // ceil(NN/256) coarse buckets (256 nodes each)
#define EPB 4096     // edges per k_part block
#define CAP 5120     // per-bucket capacity in k_sub (mean 4096, sigma 64)
#define NCOPY 16
#define SEG (NCOPY * 128)

typedef __bf16 bf16x8 __attribute__((ext_vector_type(8)));
typedef float f32x4 __attribute__((ext_vector_type(4)));
#define MFMA __builtin_amdgcn_mfma_f32_16x16x32_bf16

__device__ inline unsigned short bf_hi(float f) {
  unsigned u = __float_as_uint(f);
  unsigned r = u + 0x7FFFu + ((u >> 16) & 1u);
  return (unsigned short)(r >> 16);
}
__device__ inline float bf_to_f(unsigned short s) {
  return __uint_as_float(((unsigned)s) << 16);
}

union BF8 { bf16x8 v; unsigned short s[8]; };

__device__ inline void make_ab(const float* p, bool valid, bf16x8& hi, bf16x8& lo) {
  BF8 H, L;
  if (valid) {
    float4 f0 = *(const float4*)p;
    float4 f1 = *(const float4*)(p + 4);
    float ff[8] = {f0.x, f0.y, f0.z, f0.w, f1.x, f1.y, f1.z, f1.w};
#pragma unroll
    for (int e = 0; e < 8; ++e) {
      unsigned short h = bf_hi(ff[e]);
      H.s[e] = h;
      L.s[e] = bf_hi(ff[e] - bf_to_f(h));
    }
  } else {
#pragma unroll
    for (int e = 0; e < 8; ++e) { H.s[e] = 0; L.s[e] = 0; }
  }
  hi = H.v; lo = L.v;
}

template <int K>
__device__ inline void stage_w(const float* __restrict__ W,
                               unsigned short* __restrict__ wh,
                               unsigned short* __restrict__ wl) {
  int t = threadIdx.x;
#pragma unroll
  for (int i = 0; i < K * 64 / 256; ++i) {
    int idx = t + i * 256;
    int k = idx >> 6, c = idx & 63;
    float f = W[idx];
    unsigned short h = bf_hi(f);
    unsigned short l = bf_hi(f - bf_to_f(h));
    int off = ((k >> 5) * 4 + (c >> 4)) * 512 + (((k >> 3) & 3) * 16 + (c & 15)) * 8 + (k & 7);
    wh[off] = h;
    wl[off] = l;
  }
}

// ---------------- zero: coarse hist + BN-partials copies ----------------

__global__ void k_zero(int* __restrict__ chist, float* __restrict__ partials) {
  int i = blockIdx.x * 256 + threadIdx.x;
  if (i < NB) chist[i] = 0;
  if (i < 4 * SEG) partials[i] = 0.f;
}

// ---------------- coarse histogram (dst>>8) ----------------

__global__ __launch_bounds__(256) void k_hist(const int* __restrict__ dst,
                                              int* __restrict__ chist) {
  __shared__ int lh[NB];
  int t = threadIdx.x;
  for (int i = t; i < NB; i += 256) lh[i] = 0;
  __syncthreads();
  int e0 = blockIdx.x * EPB;
#pragma unroll
  for (int i = 0; i < EPB / 256; ++i) {
    int e = e0 + i * 256 + t;
    if (e < NE) atomicAdd(&lh[dst[e] >> 8], 1);
  }
  __syncthreads();
  for (int i = t; i < NB; i += 256)
    if (lh[i]) atomicAdd(&chist[i], lh[i]);
}

__global__ __launch_bounds__(256) void k_cscan(const int* __restrict__ chist,
                                               int* __restrict__ cbase,
                                               int* __restrict__ ccur) {
  __shared__ int ls[256];
  int t = threadIdx.x;
  int v = (t < NB) ? chist[t] : 0;
  ls[t] = v;
  __syncthreads();
  for (int off = 1; off < 256; off <<= 1) {
    int u = (t >= off) ? ls[t - off] : 0;
    __syncthreads();
    ls[t] += u;
    __syncthreads();
  }
  if (t < NB) { cbase[t] = ls[t] - v; ccur[t] = ls[t] - v; }
  if (t == 0) cbase[NB] = NE;
}

// ---------------- phase 1: partition pairs by coarse bucket (LDS-sorted) ----------------

__global__ __launch_bounds__(256) void k_part(const int* __restrict__ src,
                                              const int* __restrict__ dst,
                                              int* __restrict__ ccur,
                                              int2* __restrict__ pairs) {
  __shared__ int lh[NB];    // hist -> local exclusive base
  __shared__ int gb[NB];    // global base per bucket
  __shared__ int lc[NB];    // scatter counters
  __shared__ int ls[256];   // scan scratch
  __shared__ int2 lp[EPB];  // locally sorted pairs (32 KB)
  __shared__ int gx[EPB];   // gidx - lpos per element (16 KB)
  int t = threadIdx.x;
  for (int i = t; i < NB; i += 256) lh[i] = 0;
  __syncthreads();
  int e0 = blockIdx.x * EPB;
  int nloc = NE - e0; if (nloc > EPB) nloc = EPB;
#pragma unroll
  for (int i = 0; i < EPB / 256; ++i) {
    int e = e0 + i * 256 + t;
    if (e < NE) atomicAdd(&lh[dst[e] >> 8], 1);
  }
  __syncthreads();
  int v = (t < NB) ? lh[t] : 0;
  ls[t] = v;
  __syncthreads();
  for (int off = 1; off < 256; off <<= 1) {
    int u = (t >= off) ? ls[t - off] : 0;
    __syncthreads();
    ls[t] += u;
    __syncthreads();
  }
  int lbase = ls[t] - v;
  int gbase = 0;
  if (t < NB && v > 0) gbase = atomicAdd(&ccur[t], v);
  if (t < NB) { lh[t] = lbase; gb[t] = gbase; lc[t] = 0; }
  __syncthreads();
#pragma unroll
  for (int i = 0; i < EPB / 256; ++i) {
    int e = e0 + i * 256 + t;
    if (e < NE) {
      int d = dst[e], s = src[e];
      int b = d >> 8;
      int lpos = lh[b] + atomicAdd(&lc[b], 1);
      lp[lpos] = make_int2(s, d);
      gx[lpos] = gb[b] - lh[b];
    }
  }
  __syncthreads();
  for (int i = t; i < nloc; i += 256) pairs[gx[i] + i] = lp[i];
}

// ---------------- phase 2: exact sort within bucket -> rowptr + ebuf ----------------

__global__ __launch_bounds__(256) void k_sub(const int2* __restrict__ pairs,
                                             const int* __restrict__ cbase,
                                             int* __restrict__ rowptr,
                                             int* __restrict__ ebuf) {
  __shared__ int lh[256];    // exact local-node hist
  __shared__ int lsc[256];   // inclusive scan
  __shared__ int lc2[256];   // scatter counters
  __shared__ int ssrc[CAP];  // 20 KB sorted src
  int t = threadIdx.x;
  int b = blockIdx.x;
  int beg = cbase[b], end = cbase[b + 1];
  int n = end - beg;
  lh[t] = 0;
  lc2[t] = 0;
  __syncthreads();
  for (int i = t; i < n; i += 256) atomicAdd(&lh[pairs[beg + i].y & 255], 1);
  __syncthreads();
  int v = lh[t];
  lsc[t] = v;
  __syncthreads();
  for (int off = 1; off < 256; off <<= 1) {
    int u = (t >= off) ? lsc[t - off] : 0;
    __syncthreads();
    lsc[t] += u;
    __syncthreads();
  }
  int excl = lsc[t] - v;
  int node = b * 256 + t;
  if (node <= NN) rowptr[node] = beg + excl;
  for (int i = t; i < n; i += 256) {
    int2 p = pairs[beg + i];
    int ln = p.y & 255;
    int lpos = (lsc[ln] - lh[ln]) + atomicAdd(&lc2[ln], 1);
    if (lpos < CAP) ssrc[lpos] = p.x;
  }
  __syncthreads();
  for (int i = t; i < n; i += 256) ebuf[beg + i] = ssrc[i];
}

// ------ aggregation with fused BN affine ------

__global__ __launch_bounds__(256) void k_agg(const float* __restrict__ z,
                                             const int* __restrict__ rowptr,
                                             const int* __restrict__ ebuf,
                                             const float* __restrict__ part,
                                             const float* __restrict__ gamma,
                                             const float* __restrict__ beta,
                                             float* __restrict__ m) {
  __shared__ float sc[64], sh[64];
  int t = threadIdx.x;
  if (t < 64) {
    float s = 0.f, ss = 0.f;
#pragma unroll
    for (int c = 0; c < NCOPY; ++c) { s += part[c * 128 + t]; ss += part[c * 128 + 64 + t]; }
    float invn = 1.f / (float)NN;
    float mu = s * invn;
    float var = fmaxf(ss * invn - mu * mu, 0.f);
    float inv = rsqrtf(var + BN_EPS);
    float scale = gamma[t] * inv;
    sc[t] = scale;
    sh[t] = beta[t] - mu * scale;
  }
  __syncthreads();
  int node = blockIdx.x * 4 + (t >> 6);
  int lane = t & 63;
  int beg = rowptr[node], end = rowptr[node + 1];
  float acc = z[(size_t)node * NH + lane];
  int j = beg;
  for (; j + 3 < end; j += 4) {
    int s0 = ebuf[j], s1 = ebuf[j + 1], s2 = ebuf[j + 2], s3 = ebuf[j + 3];
    float a0 = z[(size_t)s0 * NH + lane];
    float a1 = z[(size_t)s1 * NH + lane];
    float a2 = z[(size_t)s2 * NH + lane];
    float a3 = z[(size_t)s3 * NH + lane];
    acc += (a0 + a1) + (a2 + a3);
  }
  for (; j < end; ++j) acc += z[(size_t)ebuf[j] * NH + lane];
  float deg1 = (float)(end - beg + 1);
  m[(size_t)node * NH + lane] = sc[lane] * acc + deg1 * sh[lane];
}

// ---------------- input transform (MFMA) ----------------

__global__ __launch_bounds__(256) void k_in(const float* __restrict__ x,
                                            const float* __restrict__ Wt,
                                            const float* __restrict__ bt,
                                            float* __restrict__ z,
                                            float* __restrict__ part_out) {
  __shared__ unsigned short wh[8192], wl[8192];  // 32 KB
  __shared__ float reds[16][64], redss[16][64];  // 8 KB
  int t = threadIdx.x;
  stage_w<NF>(Wt, wh, wl);
  int wv = t >> 6, lane = t & 63;
  int c15 = lane & 15, kg = lane >> 4;
  int n0 = blockIdx.x * 64 + wv * 16;
  int arow = n0 + c15;

  bf16x8 ah[4], al[4];
  const float* ap = x + (size_t)arow * NF + kg * 8;
#pragma unroll
  for (int ks = 0; ks < 4; ++ks) make_ab(ap + ks * 32, arow < NN, ah[ks], al[ks]);
  __syncthreads();

  const bf16x8* bh = (const bf16x8*)wh;
  const bf16x8* bl = (const bf16x8*)wl;
  float sAcc[4], ssAcc[4];
#pragma unroll
  for (int ct = 0; ct < 4; ++ct) {
    f32x4 acc = {0.f, 0.f, 0.f, 0.f};
#pragma unroll
    for (int ks = 0; ks < 4; ++ks) {
      bf16x8 wbh = bh[(ks * 4 + ct) * 64 + kg * 16 + c15];
      bf16x8 wbl = bl[(ks * 4 + ct) * 64 + kg * 16 + c15];
      acc = MFMA(al[ks], wbh, acc, 0, 0, 0);
      acc = MFMA(ah[ks], wbl, acc, 0, 0, 0);
      acc = MFMA(ah[ks], wbh, acc, 0, 0, 0);
    }
    float b = bt[ct * 16 + c15];
    float s = 0.f, ss = 0.f;
#pragma unroll
    for (int g = 0; g < 4; ++g) {
      int row = n0 + kg * 4 + g;
      float v = acc[g] + b;
      if (row < NN) {
        z[(size_t)row * NH + ct * 16 + c15] = v;
        s += v;
        ss += v * v;
      }
    }
    sAcc[ct] = s;
    ssAcc[ct] = ss;
  }
#pragma unroll
  for (int ct = 0; ct < 4; ++ct) {
    reds[wv * 4 + kg][ct * 16 + c15] = sAcc[ct];
    redss[wv * 4 + kg][ct * 16 + c15] = ssAcc[ct];
  }
  __syncthreads();
  if (t < 64) {
    float s2 = 0.f, ss2 = 0.f;
#pragma unroll
    for (int i = 0; i < 16; ++i) { s2 += reds[i][t]; ss2 += redss[i][t]; }
    int cp = (blockIdx.x & (NCOPY - 1)) * 128;
    atomicAdd(&part_out[cp + t], s2);
    atomicAdd(&part_out[cp + 64 + t], ss2);
  }
}

// ---------------- MLP (MFMA) ----------------

__global__ __launch_bounds__(256) void k_mlp(const float* __restrict__ m,
                                             const float* __restrict__ W1,
                                             const float* __restrict__ W2,
                                             float* __restrict__ r,
                                             float* __restrict__ part_out) {
  __shared__ unsigned short w1h[4096], w1l[4096], w2h[4096], w2l[4096];  // 32 KB
  __shared__ unsigned short tls[4][2][16][72];                           // 18.4 KB
  __shared__ float reds[16][64], redss[16][64];                          // 8 KB
  int t = threadIdx.x;
  stage_w<NH>(W1, w1h, w1l);
  stage_w<NH>(W2, w2h, w2l);
  int wv = t >> 6, lane = t & 63;
  int c15 = lane & 15, kg = lane >> 4;
  int n0 = blockIdx.x * 64 + wv * 16;
  int arow = n0 + c15;

  bf16x8 ah[2], al[2];
  const float* ap = m + (size_t)arow * NH + kg * 8;
  make_ab(ap, arow < NN, ah[0], al[0]);
  make_ab(ap + 32, arow < NN, ah[1], al[1]);
  __syncthreads();

  const bf16x8* b1h = (const bf16x8*)w1h;
  const bf16x8* b1l = (const bf16x8*)w1l;
  float tv[4][4];
#pragma unroll
  for (int ct = 0; ct < 4; ++ct) {
    f32x4 acc = {0.f, 0.f, 0.f, 0.f};
#pragma unroll
    for (int ks = 0; ks < 2; ++ks) {
      bf16x8 wbh = b1h[(ks * 4 + ct) * 64 + kg * 16 + c15];
      bf16x8 wbl = b1l[(ks * 4 + ct) * 64 + kg * 16 + c15];
      acc = MFMA(al[ks], wbh, acc, 0, 0, 0);
      acc = MFMA(ah[ks], wbl, acc, 0, 0, 0);
      acc = MFMA(ah[ks], wbh, acc, 0, 0, 0);
    }
#pragma unroll
    for (int g = 0; g < 4; ++g) tv[ct][g] = fmaxf(acc[g], 0.f);
  }
#pragma unroll
  for (int ct = 0; ct < 4; ++ct)
#pragma unroll
    for (int g = 0; g < 4; ++g) {
      int rr = kg * 4 + g, cc = ct * 16 + c15;
      unsigned short h = bf_hi(tv[ct][g]);
      tls[wv][0][rr][cc] = h;
      tls[wv][1][rr][cc] = bf_hi(tv[ct][g] - bf_to_f(h));
    }
  __syncthreads();

  bf16x8 a2h[2], a2l[2];
#pragma unroll
  for (int ks = 0; ks < 2; ++ks) {
    a2h[ks] = *(const bf16x8*)&tls[wv][0][c15][ks * 32 + kg * 8];
    a2l[ks] = *(const bf16x8*)&tls[wv][1][c15][ks * 32 + kg * 8];
  }
  const bf16x8* b2h = (const bf16x8*)w2h;
  const bf16x8* b2l = (const bf16x8*)w2l;
  float sAcc[4], ssAcc[4];
#pragma unroll
  for (int ct = 0; ct < 4; ++ct) {
    f32x4 acc = {0.f, 0.f, 0.f, 0.f};
#pragma unroll
    for (int ks = 0; ks < 2; ++ks) {
      bf16x8 wbh = b2h[(ks * 4 + ct) * 64 + kg * 16 + c15];
      bf16x8 wbl = b2l[(ks * 4 + ct) * 64 + kg * 16 + c15];
      acc = MFMA(a2l[ks], wbh, acc, 0, 0, 0);
      acc = MFMA(a2h[ks], wbl, acc, 0, 0, 0);
      acc = MFMA(a2h[ks], wbh, acc, 0, 0, 0);
    }
    float s = 0.f, ss = 0.f;
#pragma unroll
    for (int g = 0; g < 4; ++g) {
      float v = fmaxf(acc[g], 0.f);
      int row = n0 + kg * 4 + g;
      if (row < NN) r[(size_t)row * NH + ct * 16 + c15] = v;
      s += v;
      ss += v * v;
    }
    sAcc[ct] = s;
    ssAcc[ct] = ss;
  }
#pragma unroll
  for (int ct = 0; ct < 4; ++ct) {
    reds[wv * 4 + kg][ct * 16 + c15] = sAcc[ct];
    redss[wv * 4 + kg][ct * 16 + c15] = ssAcc[ct];
  }
  __syncthreads();
  if (t < 64) {
    float s2 = 0.f, ss2 = 0.f;
#pragma unroll
    for (int i = 0; i < 16; ++i) { s2 += reds[i][t]; ss2 += redss[i][t]; }
    int cp = (blockIdx.x & (NCOPY - 1)) * 128;
    atomicAdd(&part_out[cp + t], s2);
    atomicAdd(&part_out[cp + 64 + t], ss2);
  }
}

// ---------------- final BN apply ----------------

__global__ __launch_bounds__(256) void k_apply(const float* __restrict__ r,
                                               const float* __restrict__ part,
                                               const float* __restrict__ gamma,
                                               const float* __restrict__ beta,
                                               float* __restrict__ out) {
  __shared__ float sc[64], sh[64];
  int t = threadIdx.x;
  if (t < 64) {
    float s = 0.f, ss = 0.f;
#pragma unroll
    for (int c = 0; c < NCOPY; ++c) { s += part[c * 128 + t]; ss += part[c * 128 + 64 + t]; }
    float invn = 1.f / (float)NN;
    float mu = s * invn;
    float var = fmaxf(ss * invn - mu * mu, 0.f);
    float inv = rsqrtf(var + BN_EPS);
    float scale = gamma[t] * inv;
    sc[t] = scale;
    sh[t] = beta[t] - mu * scale;
  }
  __syncthreads();
  int i = blockIdx.x * 256 + t;  // float4 index
  if (i < NN * (NH / 4)) {
    int c0 = (i * 4) & 63;
    float4 v = ((const float4*)r)[i];
    float4 o;
    o.x = v.x * sc[c0 + 0] + sh[c0 + 0];
    o.y = v.y * sc[c0 + 1] + sh[c0 + 1];
    o.z = v.z * sc[c0 + 2] + sh[c0 + 2];
    o.w = v.w * sc[c0 + 3] + sh[c0 + 3];
    ((float4*)out)[i] = o;
  }
}

// ---------------- launch ----------------

extern "C" void kernel_launch(void* const* d_in, const int* in_sizes, int n_in,
                              void* d_out, int out_size, void* d_ws, size_t ws_size,
                              hipStream_t stream) {
  (void)in_sizes; (void)n_in; (void)out_size; (void)ws_size;
  const float* x      = (const float*)d_in[0];
  const int*   ei     = (const int*)d_in[1];
  const float* Wt     = (const float*)d_in[2];
  const float* bt     = (const float*)d_in[3];
  const float* gt     = (const float*)d_in[4];
  const float* bet    = (const float*)d_in[5];
  const float* Ws1    = (const float*)d_in[6];
  const float* Ws2    = (const float*)d_in[7];
  const float* gammas = (const float*)d_in[8];
  const float* betas  = (const float*)d_in[9];

  const int* esrc = ei;
  const int* edst = ei + NE;

  float* bufA     = (float*)d_ws;                     // 3.2M floats (pairs aliased here)
  float* bufB     = bufA + (size_t)NN * NH;           // 3.2M floats
  int*   ebuf     = (int*)(bufB + (size_t)NN * NH);   // NE
  int*   rowptr   = ebuf + NE;                        // NN+1
  int*   chist    = rowptr + NN + 1;                  // NB
  int*   cbase    = chist + NB;                       // NB+1
  int*   ccur     = cbase + NB + 1;                   // NB
  float* partials = (float*)(ccur + NB);              // 4 segments x NCOPY x 128
  int2*  pairs    = (int2*)bufA;                      // NE int2, dead before k_in

  const int GB = (NN + 63) / 64;  // 782

  // CSR build (two-phase bucketed sort by dst)
  k_zero<<<(4 * SEG + 255) / 256, 256, 0, stream>>>(chist, partials);
  k_hist<<<(NE + EPB - 1) / EPB, 256, 0, stream>>>(edst, chist);
  k_cscan<<<1, 256, 0, stream>>>(chist, cbase, ccur);
  k_part<<<(NE + EPB - 1) / EPB, 256, 0, stream>>>(esrc, edst, ccur, pairs);
  k_sub<<<NB, 256, 0, stream>>>(pairs, cbase, rowptr, ebuf);

  // input transform (raw z + stats -> seg 0)
  k_in<<<GB, 256, 0, stream>>>(x, Wt, bt, bufA, partials);

  // L0
  k_agg<<<NN / 4, 256, 0, stream>>>(bufA, rowptr, ebuf, partials, gt, bet, bufB);
  k_mlp<<<GB, 256, 0, stream>>>(bufB, Ws1, Ws2, bufB, partials + SEG);

  // L1
  k_agg<<<NN / 4, 256, 0, stream>>>(bufB, rowptr, ebuf, partials + SEG, gammas, betas, bufA);
  k_mlp<<<GB, 256, 0, stream>>>(bufA, Ws1 + NH * NH, Ws2 + NH * NH, bufA, partials + 2 * SEG);

  // L2
  k_agg<<<NN / 4, 256, 0, stream>>>(bufA, rowptr, ebuf, partials + 2 * SEG, gammas + NH,
                                    betas + NH, bufB);
  k_mlp<<<GB, 256, 0, stream>>>(bufB, Ws1 + 2 * NH * NH, Ws2 + 2 * NH * NH, bufB,
                                partials + 3 * SEG);

  // final BN apply -> d_out
  k_apply<<<(NN * (NH / 4) + 255) / 256, 256, 0, stream>>>(bufB, partials + 3 * SEG,
                                                           gammas + 2 * NH, betas + 2 * NH,
                                                           (float*)d_out);
}

// Round 6
// 218.044 us; speedup vs baseline: 2.9718x; 1.0304x over previous
//
#include <hip/hip_runtime.h>

#define NN 50000
#define NE 800000
#define NF 128
#define NH 64
#define BN_EPS 1e-5f
#define NB 196       // ceil(NN/256) coarse buckets (256 nodes each)
#define EPB 4096     // edges per k_part block
#define CAP 5120     // per-bucket capacity in k_sub (mean 4096, +16 sigma)
#define NCOPY 16
#define SEG (NCOPY * 128)

typedef __bf16 bf16x8 __attribute__((ext_vector_type(8)));
typedef float f32x4 __attribute__((ext_vector_type(4)));
#define MFMA __builtin_amdgcn_mfma_f32_16x16x32_bf16

__device__ inline unsigned short bf_hi(float f) {
  unsigned u = __float_as_uint(f);
  unsigned r = u + 0x7FFFu + ((u >> 16) & 1u);
  return (unsigned short)(r >> 16);
}
__device__ inline float bf_to_f(unsigned short s) {
  return __uint_as_float(((unsigned)s) << 16);
}

union BF8 { bf16x8 v; unsigned short s[8]; };

__device__ inline void make_ab(const float* p, bool valid, bf16x8& hi, bf16x8& lo) {
  BF8 H, L;
  if (valid) {
    float4 f0 = *(const float4*)p;
    float4 f1 = *(const float4*)(p + 4);
    float ff[8] = {f0.x, f0.y, f0.z, f0.w, f1.x, f1.y, f1.z, f1.w};
#pragma unroll
    for (int e = 0; e < 8; ++e) {
      unsigned short h = bf_hi(ff[e]);
      H.s[e] = h;
      L.s[e] = bf_hi(ff[e] - bf_to_f(h));
    }
  } else {
#pragma unroll
    for (int e = 0; e < 8; ++e) { H.s[e] = 0; L.s[e] = 0; }
  }
  hi = H.v; lo = L.v;
}

template <int K>
__device__ inline void stage_w(const float* __restrict__ W,
                               unsigned short* __restrict__ wh,
                               unsigned short* __restrict__ wl) {
  int t = threadIdx.x;
#pragma unroll
  for (int i = 0; i < K * 64 / 256; ++i) {
    int idx = t + i * 256;
    int k = idx >> 6, c = idx & 63;
    float f = W[idx];
    unsigned short h = bf_hi(f);
    unsigned short l = bf_hi(f - bf_to_f(h));
    int off = ((k >> 5) * 4 + (c >> 4)) * 512 + (((k >> 3) & 3) * 16 + (c & 15)) * 8 + (k & 7);
    wh[off] = h;
    wl[off] = l;
  }
}

// ---------------- zero: coarse hist + BN-partials copies ----------------

__global__ void k_zero(int* __restrict__ chist, float* __restrict__ partials) {
  int i = blockIdx.x * 256 + threadIdx.x;
  if (i < NB) chist[i] = 0;
  if (i < 4 * SEG) partials[i] = 0.f;
}

// ---------------- coarse histogram (dst>>8) ----------------

__global__ __launch_bounds__(256) void k_hist(const int* __restrict__ dst,
                                              int* __restrict__ chist) {
  __shared__ int lh[NB];
  int t = threadIdx.x;
  for (int i = t; i < NB; i += 256) lh[i] = 0;
  __syncthreads();
  int e0 = blockIdx.x * EPB;
#pragma unroll
  for (int i = 0; i < EPB / 256; ++i) {
    int e = e0 + i * 256 + t;
    if (e < NE) atomicAdd(&lh[dst[e] >> 8], 1);
  }
  __syncthreads();
  for (int i = t; i < NB; i += 256)
    if (lh[i]) atomicAdd(&chist[i], lh[i]);
}

__global__ __launch_bounds__(256) void k_cscan(const int* __restrict__ chist,
                                               int* __restrict__ cbase,
                                               int* __restrict__ ccur) {
  __shared__ int ls[256];
  int t = threadIdx.x;
  int v = (t < NB) ? chist[t] : 0;
  ls[t] = v;
  __syncthreads();
  for (int off = 1; off < 256; off <<= 1) {
    int u = (t >= off) ? ls[t - off] : 0;
    __syncthreads();
    ls[t] += u;
    __syncthreads();
  }
  if (t < NB) { cbase[t] = ls[t] - v; ccur[t] = ls[t] - v; }
  if (t == 0) cbase[NB] = NE;
}

// -------- phase 1: partition packed records by coarse bucket (LDS-sorted) --------
// record = (dst & 255) << 16 | src   (src < 65536, in-bucket dst is 8 bits)

__global__ __launch_bounds__(256) void k_part(const int* __restrict__ src,
                                              const int* __restrict__ dst,
                                              int* __restrict__ ccur,
                                              int* __restrict__ pairs) {
  __shared__ int lh[NB];    // hist -> local exclusive base
  __shared__ int gb[NB];    // global base per bucket
  __shared__ int lc[NB];    // scatter counters
  __shared__ int ls[256];   // scan scratch
  __shared__ int lp[EPB];   // locally sorted packed records (16 KB)
  __shared__ int gx[EPB];   // gidx - lpos per element (16 KB)
  int t = threadIdx.x;
  for (int i = t; i < NB; i += 256) lh[i] = 0;
  __syncthreads();
  int e0 = blockIdx.x * EPB;
  int nloc = NE - e0; if (nloc > EPB) nloc = EPB;
#pragma unroll
  for (int i = 0; i < EPB / 256; ++i) {
    int e = e0 + i * 256 + t;
    if (e < NE) atomicAdd(&lh[dst[e] >> 8], 1);
  }
  __syncthreads();
  int v = (t < NB) ? lh[t] : 0;
  ls[t] = v;
  __syncthreads();
  for (int off = 1; off < 256; off <<= 1) {
    int u = (t >= off) ? ls[t - off] : 0;
    __syncthreads();
    ls[t] += u;
    __syncthreads();
  }
  int lbase = ls[t] - v;
  int gbase = 0;
  if (t < NB && v > 0) gbase = atomicAdd(&ccur[t], v);
  if (t < NB) { lh[t] = lbase; gb[t] = gbase; lc[t] = 0; }
  __syncthreads();
#pragma unroll
  for (int i = 0; i < EPB / 256; ++i) {
    int e = e0 + i * 256 + t;
    if (e < NE) {
      int d = dst[e], s = src[e];
      int b = d >> 8;
      int lpos = lh[b] + atomicAdd(&lc[b], 1);
      lp[lpos] = ((d & 255) << 16) | s;
      gx[lpos] = gb[b] - lh[b];
    }
  }
  __syncthreads();
  for (int i = t; i < nloc; i += 256) pairs[gx[i] + i] = lp[i];
}

// ---------------- phase 2: exact sort within bucket -> rowptr + ebuf ----------------

__global__ __launch_bounds__(256) void k_sub(const int* __restrict__ pairs,
                                             const int* __restrict__ cbase,
                                             int* __restrict__ rowptr,
                                             int* __restrict__ ebuf) {
  __shared__ int lh[256];
  __shared__ int lsc[256];
  __shared__ int lc2[256];
  __shared__ unsigned short ssrc[CAP];  // 10 KB sorted src
  int t = threadIdx.x;
  int b = blockIdx.x;
  int beg = cbase[b], end = cbase[b + 1];
  int n = end - beg;
  lh[t] = 0;
  lc2[t] = 0;
  __syncthreads();
  for (int i = t; i < n; i += 256) atomicAdd(&lh[(pairs[beg + i] >> 16) & 255], 1);
  __syncthreads();
  int v = lh[t];
  lsc[t] = v;
  __syncthreads();
  for (int off = 1; off < 256; off <<= 1) {
    int u = (t >= off) ? lsc[t - off] : 0;
    __syncthreads();
    lsc[t] += u;
    __syncthreads();
  }
  int excl = lsc[t] - v;
  int node = b * 256 + t;
  if (node <= NN) rowptr[node] = beg + excl;
  for (int i = t; i < n; i += 256) {
    int p = pairs[beg + i];
    int ln = (p >> 16) & 255;
    int lpos = (lsc[ln] - lh[ln]) + atomicAdd(&lc2[ln], 1);
    if (lpos < CAP) ssrc[lpos] = (unsigned short)(p & 0xFFFF);
  }
  __syncthreads();
  for (int i = t; i < n; i += 256) ebuf[beg + i] = (int)ssrc[i];
}

// ------ aggregation (bf16 gather) with fused BN affine:
// m[i] = scale .* (z[i] + sum_j zb[j]) + (deg_i + 1) * shift ------

__global__ __launch_bounds__(256) void k_agg(const float* __restrict__ z,
                                             const unsigned short* __restrict__ zb,
                                             const int* __restrict__ rowptr,
                                             const int* __restrict__ ebuf,
                                             const float* __restrict__ part,
                                             const float* __restrict__ gamma,
                                             const float* __restrict__ beta,
                                             float* __restrict__ m) {
  __shared__ float sc[64], sh[64];
  int t = threadIdx.x;
  if (t < 64) {
    float s = 0.f, ss = 0.f;
#pragma unroll
    for (int c = 0; c < NCOPY; ++c) { s += part[c * 128 + t]; ss += part[c * 128 + 64 + t]; }
    float invn = 1.f / (float)NN;
    float mu = s * invn;
    float var = fmaxf(ss * invn - mu * mu, 0.f);
    float inv = rsqrtf(var + BN_EPS);
    float scale = gamma[t] * inv;
    sc[t] = scale;
    sh[t] = beta[t] - mu * scale;
  }
  __syncthreads();
  int lane = t & 63;
  int node = blockIdx.x * 4 + (t >> 6);
  int half = lane >> 5;   // 0/1: which edge of the pair
  int l32 = lane & 31;    // channel-pair index (ch 2*l32, 2*l32+1)
  int beg = rowptr[node], end = rowptr[node + 1];
  // self term in fp32 (both halves read the same float2 -> broadcast; added in half 0 only)
  float2 selfv = ((const float2*)(z + (size_t)node * NH))[l32];
  float a0 = half ? 0.f : selfv.x;
  float a1 = half ? 0.f : selfv.y;
  int j = beg + half;
  for (; j + 2 < end; j += 4) {
    int s0 = ebuf[j];
    int s1 = ebuf[j + 2];
    unsigned u0 = *(const unsigned*)(zb + (size_t)s0 * NH + 2 * l32);
    unsigned u1 = *(const unsigned*)(zb + (size_t)s1 * NH + 2 * l32);
    a0 += bf_to_f((unsigned short)(u0 & 0xFFFF)) + bf_to_f((unsigned short)(u1 & 0xFFFF));
    a1 += bf_to_f((unsigned short)(u0 >> 16)) + bf_to_f((unsigned short)(u1 >> 16));
  }
  for (; j < end; j += 2) {
    int s0 = ebuf[j];
    unsigned u0 = *(const unsigned*)(zb + (size_t)s0 * NH + 2 * l32);
    a0 += bf_to_f((unsigned short)(u0 & 0xFFFF));
    a1 += bf_to_f((unsigned short)(u0 >> 16));
  }
  a0 += __shfl_xor(a0, 32);
  a1 += __shfl_xor(a1, 32);
  if (half == 0) {
    float deg1 = (float)(end - beg + 1);
    int c0 = 2 * l32;
    float2 o;
    o.x = sc[c0] * a0 + deg1 * sh[c0];
    o.y = sc[c0 + 1] * a1 + deg1 * sh[c0 + 1];
    ((float2*)(m + (size_t)node * NH))[l32] = o;
  }
}

// ---------------- input transform (MFMA): z = x @ Wt + bt (+bf16 plane, stats) ----------------

__global__ __launch_bounds__(256) void k_in(const float* __restrict__ x,
                                            const float* __restrict__ Wt,
                                            const float* __restrict__ bt,
                                            float* __restrict__ z,
                                            unsigned short* __restrict__ zb,
                                            float* __restrict__ part_out) {
  __shared__ unsigned short wh[8192], wl[8192];  // 32 KB
  __shared__ float reds[16][64], redss[16][64];  // 8 KB
  int t = threadIdx.x;
  stage_w<NF>(Wt, wh, wl);
  int wv = t >> 6, lane = t & 63;
  int c15 = lane & 15, kg = lane >> 4;
  int n0 = blockIdx.x * 64 + wv * 16;
  int arow = n0 + c15;

  bf16x8 ah[4], al[4];
  const float* ap = x + (size_t)arow * NF + kg * 8;
#pragma unroll
  for (int ks = 0; ks < 4; ++ks) make_ab(ap + ks * 32, arow < NN, ah[ks], al[ks]);
  __syncthreads();

  const bf16x8* bh = (const bf16x8*)wh;
  const bf16x8* bl = (const bf16x8*)wl;
  float sAcc[4], ssAcc[4];
#pragma unroll
  for (int ct = 0; ct < 4; ++ct) {
    f32x4 acc = {0.f, 0.f, 0.f, 0.f};
#pragma unroll
    for (int ks = 0; ks < 4; ++ks) {
      bf16x8 wbh = bh[(ks * 4 + ct) * 64 + kg * 16 + c15];
      bf16x8 wbl = bl[(ks * 4 + ct) * 64 + kg * 16 + c15];
      acc = MFMA(al[ks], wbh, acc, 0, 0, 0);
      acc = MFMA(ah[ks], wbl, acc, 0, 0, 0);
      acc = MFMA(ah[ks], wbh, acc, 0, 0, 0);
    }
    float b = bt[ct * 16 + c15];
    float s = 0.f, ss = 0.f;
#pragma unroll
    for (int g = 0; g < 4; ++g) {
      int row = n0 + kg * 4 + g;
      float v = acc[g] + b;
      if (row < NN) {
        z[(size_t)row * NH + ct * 16 + c15] = v;
        zb[(size_t)row * NH + ct * 16 + c15] = bf_hi(v);
        s += v;
        ss += v * v;
      }
    }
    sAcc[ct] = s;
    ssAcc[ct] = ss;
  }
#pragma unroll
  for (int ct = 0; ct < 4; ++ct) {
    reds[wv * 4 + kg][ct * 16 + c15] = sAcc[ct];
    redss[wv * 4 + kg][ct * 16 + c15] = ssAcc[ct];
  }
  __syncthreads();
  if (t < 64) {
    float s2 = 0.f, ss2 = 0.f;
#pragma unroll
    for (int i = 0; i < 16; ++i) { s2 += reds[i][t]; ss2 += redss[i][t]; }
    int cp = (blockIdx.x & (NCOPY - 1)) * 128;
    atomicAdd(&part_out[cp + t], s2);
    atomicAdd(&part_out[cp + 64 + t], ss2);
  }
}

// ---------------- MLP (MFMA): r = relu(relu(m@W1)@W2) (+bf16 plane, stats) ----------------

__global__ __launch_bounds__(256) void k_mlp(const float* __restrict__ m,
                                             const float* __restrict__ W1,
                                             const float* __restrict__ W2,
                                             float* __restrict__ r,
                                             unsigned short* __restrict__ rb,
                                             float* __restrict__ part_out) {
  __shared__ unsigned short w1h[4096], w1l[4096], w2h[4096], w2l[4096];  // 32 KB
  __shared__ unsigned short tls[4][2][16][72];                           // 18.4 KB
  __shared__ float reds[16][64], redss[16][64];                          // 8 KB
  int t = threadIdx.x;
  stage_w<NH>(W1, w1h, w1l);
  stage_w<NH>(W2, w2h, w2l);
  int wv = t >> 6, lane = t & 63;
  int c15 = lane & 15, kg = lane >> 4;
  int n0 = blockIdx.x * 64 + wv * 16;
  int arow = n0 + c15;

  bf16x8 ah[2], al[2];
  const float* ap = m + (size_t)arow * NH + kg * 8;
  make_ab(ap, arow < NN, ah[0], al[0]);
  make_ab(ap + 32, arow < NN, ah[1], al[1]);
  __syncthreads();

  const bf16x8* b1h = (const bf16x8*)w1h;
  const bf16x8* b1l = (const bf16x8*)w1l;
  float tv[4][4];
#pragma unroll
  for (int ct = 0; ct < 4; ++ct) {
    f32x4 acc = {0.f, 0.f, 0.f, 0.f};
#pragma unroll
    for (int ks = 0; ks < 2; ++ks) {
      bf16x8 wbh = b1h[(ks * 4 + ct) * 64 + kg * 16 + c15];
      bf16x8 wbl = b1l[(ks * 4 + ct) * 64 + kg * 16 + c15];
      acc = MFMA(al[ks], wbh, acc, 0, 0, 0);
      acc = MFMA(ah[ks], wbl, acc, 0, 0, 0);
      acc = MFMA(ah[ks], wbh, acc, 0, 0, 0);
    }
#pragma unroll
    for (int g = 0; g < 4; ++g) tv[ct][g] = fmaxf(acc[g], 0.f);
  }
#pragma unroll
  for (int ct = 0; ct < 4; ++ct)
#pragma unroll
    for (int g = 0; g < 4; ++g) {
      int rr = kg * 4 + g, cc = ct * 16 + c15;
      unsigned short h = bf_hi(tv[ct][g]);
      tls[wv][0][rr][cc] = h;
      tls[wv][1][rr][cc] = bf_hi(tv[ct][g] - bf_to_f(h));
    }
  __syncthreads();

  bf16x8 a2h[2], a2l[2];
#pragma unroll
  for (int ks = 0; ks < 2; ++ks) {
    a2h[ks] = *(const bf16x8*)&tls[wv][0][c15][ks * 32 + kg * 8];
    a2l[ks] = *(const bf16x8*)&tls[wv][1][c15][ks * 32 + kg * 8];
  }
  const bf16x8* b2h = (const bf16x8*)w2h;
  const bf16x8* b2l = (const bf16x8*)w2l;
  float sAcc[4], ssAcc[4];
#pragma unroll
  for (int ct = 0; ct < 4; ++ct) {
    f32x4 acc = {0.f, 0.f, 0.f, 0.f};
#pragma unroll
    for (int ks = 0; ks < 2; ++ks) {
      bf16x8 wbh = b2h[(ks * 4 + ct) * 64 + kg * 16 + c15];
      bf16x8 wbl = b2l[(ks * 4 + ct) * 64 + kg * 16 + c15];
      acc = MFMA(a2l[ks], wbh, acc, 0, 0, 0);
      acc = MFMA(a2h[ks], wbl, acc, 0, 0, 0);
      acc = MFMA(a2h[ks], wbh, acc, 0, 0, 0);
    }
    float s = 0.f, ss = 0.f;
#pragma unroll
    for (int g = 0; g < 4; ++g) {
      float v = fmaxf(acc[g], 0.f);
      int row = n0 + kg * 4 + g;
      if (row < NN) {
        r[(size_t)row * NH + ct * 16 + c15] = v;
        rb[(size_t)row * NH + ct * 16 + c15] = bf_hi(v);
      }
      s += v;
      ss += v * v;
    }
    sAcc[ct] = s;
    ssAcc[ct] = ss;
  }
#pragma unroll
  for (int ct = 0; ct < 4; ++ct) {
    reds[wv * 4 + kg][ct * 16 + c15] = sAcc[ct];
    redss[wv * 4 + kg][ct * 16 + c15] = ssAcc[ct];
  }
  __syncthreads();
  if (t < 64) {
    float s2 = 0.f, ss2 = 0.f;
#pragma unroll
    for (int i = 0; i < 16; ++i) { s2 += reds[i][t]; ss2 += redss[i][t]; }
    int cp = (blockIdx.x & (NCOPY - 1)) * 128;
    atomicAdd(&part_out[cp + t], s2);
    atomicAdd(&part_out[cp + 64 + t], ss2);
  }
}

// ---------------- final BN apply ----------------

__global__ __launch_bounds__(256) void k_apply(const float* __restrict__ r,
                                               const float* __restrict__ part,
                                               const float* __restrict__ gamma,
                                               const float* __restrict__ beta,
                                               float* __restrict__ out) {
  __shared__ float sc[64], sh[64];
  int t = threadIdx.x;
  if (t < 64) {
    float s = 0.f, ss = 0.f;
#pragma unroll
    for (int c = 0; c < NCOPY; ++c) { s += part[c * 128 + t]; ss += part[c * 128 + 64 + t]; }
    float invn = 1.f / (float)NN;
    float mu = s * invn;
    float var = fmaxf(ss * invn - mu * mu, 0.f);
    float inv = rsqrtf(var + BN_EPS);
    float scale = gamma[t] * inv;
    sc[t] = scale;
    sh[t] = beta[t] - mu * scale;
  }
  __syncthreads();
  int i = blockIdx.x * 256 + t;  // float4 index
  if (i < NN * (NH / 4)) {
    int c0 = (i * 4) & 63;
    float4 v = ((const float4*)r)[i];
    float4 o;
    o.x = v.x * sc[c0 + 0] + sh[c0 + 0];
    o.y = v.y * sc[c0 + 1] + sh[c0 + 1];
    o.z = v.z * sc[c0 + 2] + sh[c0 + 2];
    o.w = v.w * sc[c0 + 3] + sh[c0 + 3];
    ((float4*)out)[i] = o;
  }
}

// ---------------- launch ----------------

extern "C" void kernel_launch(void* const* d_in, const int* in_sizes, int n_in,
                              void* d_out, int out_size, void* d_ws, size_t ws_size,
                              hipStream_t stream) {
  (void)in_sizes; (void)n_in; (void)out_size; (void)ws_size;
  const float* x      = (const float*)d_in[0];
  const int*   ei     = (const int*)d_in[1];
  const float* Wt     = (const float*)d_in[2];
  const float* bt     = (const float*)d_in[3];
  const float* gt     = (const float*)d_in[4];
  const float* bet    = (const float*)d_in[5];
  const float* Ws1    = (const float*)d_in[6];
  const float* Ws2    = (const float*)d_in[7];
  const float* gammas = (const float*)d_in[8];
  const float* betas  = (const float*)d_in[9];

  const int* esrc = ei;
  const int* edst = ei + NE;

  float*          bufA     = (float*)d_ws;                     // 3.2M floats (pairs aliased)
  float*          bufB     = bufA + (size_t)NN * NH;           // 3.2M floats
  int*            ebuf     = (int*)(bufB + (size_t)NN * NH);   // NE
  int*            rowptr   = ebuf + NE;                        // NN+1
  int*            chist    = rowptr + NN + 1;                  // NB
  int*            cbase    = chist + NB;                       // NB+1
  int*            ccur     = cbase + NB + 1;                   // NB
  float*          partials = (float*)(ccur + NB);              // 4 x SEG
  unsigned short* bfA      = (unsigned short*)(partials + 4 * SEG);  // NN*NH bf16
  unsigned short* bfB      = bfA + (size_t)NN * NH;                  // NN*NH bf16
  int*            pairs    = (int*)bufA;                       // NE ints, dead before k_in

  const int GB = (NN + 63) / 64;  // 782

  // CSR build (two-phase bucketed sort by dst, packed records)
  k_zero<<<(4 * SEG + 255) / 256, 256, 0, stream>>>(chist, partials);
  k_hist<<<(NE + EPB - 1) / EPB, 256, 0, stream>>>(edst, chist);
  k_cscan<<<1, 256, 0, stream>>>(chist, cbase, ccur);
  k_part<<<(NE + EPB - 1) / EPB, 256, 0, stream>>>(esrc, edst, ccur, pairs);
  k_sub<<<NB, 256, 0, stream>>>(pairs, cbase, rowptr, ebuf);

  // input transform (z fp32 + bf16 plane + stats seg0)
  k_in<<<GB, 256, 0, stream>>>(x, Wt, bt, bufA, bfA, partials);

  // L0
  k_agg<<<NN / 4, 256, 0, stream>>>(bufA, bfA, rowptr, ebuf, partials, gt, bet, bufB);
  k_mlp<<<GB, 256, 0, stream>>>(bufB, Ws1, Ws2, bufB, bfB, partials + SEG);

  // L1
  k_agg<<<NN / 4, 256, 0, stream>>>(bufB, bfB, rowptr, ebuf, partials + SEG, gammas, betas,
                                    bufA);
  k_mlp<<<GB, 256, 0, stream>>>(bufA, Ws1 + NH * NH, Ws2 + NH * NH, bufA, bfA,
                                partials + 2 * SEG);

  // L2
  k_agg<<<NN / 4, 256, 0, stream>>>(bufA, bfA, rowptr, ebuf, partials + 2 * SEG, gammas + NH,
                                    betas + NH, bufB);
  k_mlp<<<GB, 256, 0, stream>>>(bufB, Ws1 + 2 * NH * NH, Ws2 + 2 * NH * NH, bufB, bfB,
                                partials + 3 * SEG);

  // final BN apply -> d_out
  k_apply<<<(NN * (NH / 4) + 255) / 256, 256, 0, stream>>>(bufB, partials + 3 * SEG,
                                                           gammas + 2 * NH, betas + 2 * NH,
                                                           (float*)d_out);
}